// Round 7
// baseline (517.854 us; speedup 1.0000x reference)
//
#include <hip/hip_runtime.h>

// StockLSTM: A=weights / B=state MFMA layout so gate nonlinearity + cell
// update are in-register. 1024-thread blocks (16 waves, 4/SIMD), wave w owns
// hidden units j in [4w,4w+4) across all 4 gate groups; 2 barriers/step with
// t-parity double-buffered h state. bf16 hi/lo 3-term MFMA.
// R6 lesson: VGPR budget appears fixed at ~128 unified (64v+64a) regardless of
// waves_per_eu; R4-R6 spilled ~36 dwords/thread (32-38 MB scratch WRITE_SIZE).
// This round cuts demand: x-term folded into the MFMA K-dim (kills Wx[4][5]
// = 20 VGPRs + 40 VALU FMAs/step, adds Axw frag = 8 VGPRs + 3 MFMAs/step).

#define TT   256
#define II   5
#define HH   64
#define OO   25
#define MT   16        // batch rows per block (MFMA n-dim)
#define NTHR 1024
#define XR   325       // xs row stride (floats): 320 + 5 skew
#define HR   72        // h row stride (ushorts): 64 + 8 pad (16B aligned)
#define HF   65        // h2f row stride (floats)

typedef __attribute__((ext_vector_type(8))) short  short8;
typedef __attribute__((ext_vector_type(4))) float  floatx4;

#define MFMA(a, b, c) __builtin_amdgcn_mfma_f32_16x16x32_bf16(a, b, c, 0, 0, 0)

__device__ __forceinline__ float frcp(float x) { return __builtin_amdgcn_rcpf(x); }
__device__ __forceinline__ float fsig(float x) {
    return frcp(1.f + __builtin_amdgcn_exp2f(x * -1.44269504f));
}
__device__ __forceinline__ float ftanhf(float x) {
    return 1.f - 2.f * frcp(1.f + __builtin_amdgcn_exp2f(x * 2.88539008f));
}
__device__ __forceinline__ unsigned short bf16_rne(float f) {
    unsigned int u = __builtin_bit_cast(unsigned int, f);
    u += 0x7FFFu + ((u >> 16) & 1u);
    return (unsigned short)(u >> 16);
}
__device__ __forceinline__ float bf16_f(unsigned short h) {
    unsigned int u = ((unsigned int)h) << 16;
    return __builtin_bit_cast(float, u);
}
struct HiLo { short hi, lo; };
__device__ __forceinline__ HiLo split2(float v) {
    HiLo r;
    unsigned short h = bf16_rne(v);
    r.hi = (short)h;
    r.lo = (short)bf16_rne(v - bf16_f(h));
    return r;
}

__global__ __attribute__((amdgpu_flat_work_group_size(1024, 1024),
                          amdgpu_waves_per_eu(4, 4)))
void lstm_mfma3(const float* __restrict__ x,
                const float* __restrict__ Wih0, const float* __restrict__ Whh0,
                const float* __restrict__ bih0, const float* __restrict__ bhh0,
                const float* __restrict__ Wih1, const float* __restrict__ Whh1,
                const float* __restrict__ bih1, const float* __restrict__ bhh1,
                const float* __restrict__ Wfc,  const float* __restrict__ bfc,
                float* __restrict__ out)
{
    __shared__ __align__(16) float          xs[MT * XR];          // 20.8 KB
    __shared__ __align__(16) unsigned short h1hi[2][MT * HR];
    __shared__ __align__(16) unsigned short h1lo[2][MT * HR];
    __shared__ __align__(16) unsigned short h2hi[2][MT * HR];
    __shared__ __align__(16) unsigned short h2lo[2][MT * HR];
    __shared__ __align__(16) float          h2f[MT * HF];

    const int tid   = threadIdx.x;
    const int w     = tid >> 6;       // wave 0..15
    const int lane  = tid & 63;
    const int b     = lane & 15;      // batch col (B n-dim / C col)
    const int q     = lane >> 4;      // k-slice selector / C row-quad
    const int jmine = 4 * w + q;      // this lane's hidden unit
    const int hw_off = b * HR + jmine;

    // ---------------- A-fragment (weight) preload ----------------
    // Tile row m in [0,16): gate group = m&3, hidden j = 4w + (m>>2).
    // A layout: lane holds A[m = lane&15][k = q*8 + jj].
    short8 A1h[2], A1l[2];   // Whh0 k-chunks
    short8 A2h[4], A2l[4];   // chunks 0,1: Wih1 (h1 side); 2,3: Whh1 (h2 side)
    short8 Axwh, Axwl;       // Wih0 chunk: k<II valid, rest zero
    {
        const int rr = lane & 15;
        const int g  = (rr & 3) * 64 + 4 * w + (rr >> 2);
        #pragma unroll
        for (int c = 0; c < 2; ++c)
            #pragma unroll
            for (int jj = 0; jj < 8; ++jj) {
                HiLo s = split2(Whh0[g * HH + c * 32 + q * 8 + jj]);
                A1h[c][jj] = s.hi; A1l[c][jj] = s.lo;
            }
        #pragma unroll
        for (int c = 0; c < 4; ++c)
            #pragma unroll
            for (int jj = 0; jj < 8; ++jj) {
                const int k = c * 32 + q * 8 + jj;
                float wv = (k < HH) ? Wih1[g * HH + k] : Whh1[g * HH + (k - HH)];
                HiLo s = split2(wv);
                A2h[c][jj] = s.hi; A2l[c][jj] = s.lo;
            }
        #pragma unroll
        for (int jj = 0; jj < 8; ++jj) {
            const int k = q * 8 + jj;
            float wv = (k < II) ? Wih0[g * II + k] : 0.f;
            HiLo s = split2(wv);
            Axwh[jj] = s.hi; Axwl[jj] = s.lo;
        }
    }
    // biases, indexed by acc reg r: acc[r] <-> gate row r*64 + jmine.
    float bias1[4], bias2[4];
    #pragma unroll
    for (int r = 0; r < 4; ++r) {
        const int g = r * 64 + jmine;
        bias1[r] = bih0[g] + bhh0[g];
        bias2[r] = bih1[g] + bhh1[g];
    }

    // ---------------- zero h state (both parities) ----------------
    {
        unsigned int* z1 = (unsigned int*)h1hi;
        unsigned int* z2 = (unsigned int*)h1lo;
        unsigned int* z3 = (unsigned int*)h2hi;
        unsigned int* z4 = (unsigned int*)h2lo;
        for (int i = tid; i < MT * HR; i += NTHR) {
            z1[i] = 0u; z2[i] = 0u; z3[i] = 0u; z4[i] = 0u;
        }
    }
    float c1 = 0.f, c2 = 0.f;
    __syncthreads();

    for (int t = 0; t < TT; ++t) {
        // ---- refill 64-step x chunk (wave w loads batch row w) ----
        if ((t & 63) == 0) {
            const float* src = x + ((size_t)(blockIdx.x * MT + w) * TT + t) * II;
            float* dst = xs + w * XR;
            #pragma unroll
            for (int i = 0; i < 5; ++i) dst[lane + i * 64] = src[lane + i * 64];
            __syncthreads();
        }
        const int dt = t & 63;
        const int wp = t & 1, rp = wp ^ 1;
        const int off0 = b * HR + q * 8, off1 = off0 + 32;

        // ================= Layer 1 =================
        // x enters as B-fragment rows k=0..4 (only q==0 lanes hold data).
        short8 Bxh = {0,0,0,0,0,0,0,0}, Bxl = {0,0,0,0,0,0,0,0};
        if (q == 0) {
            const float* xv = xs + b * XR + dt * II;
            #pragma unroll
            for (int i = 0; i < II; ++i) {
                HiLo s = split2(xv[i]);
                Bxh[i] = s.hi; Bxl[i] = s.lo;
            }
        }
        floatx4 accA = {bias1[0], bias1[1], bias1[2], bias1[3]};
        floatx4 accB = {0.f, 0.f, 0.f, 0.f};
        accA = MFMA(Axwh, Bxh, accA);
        accA = MFMA(Axwh, Bxl, accA);
        accA = MFMA(Axwl, Bxh, accA);
        {
            short8 Bh0 = *(const short8*)(&h1hi[rp][off0]);
            short8 Bl0 = *(const short8*)(&h1lo[rp][off0]);
            short8 Bh1 = *(const short8*)(&h1hi[rp][off1]);
            short8 Bl1 = *(const short8*)(&h1lo[rp][off1]);
            accB = MFMA(A1h[0], Bh0, accB);
            accB = MFMA(A1h[0], Bl0, accB);
            accB = MFMA(A1l[0], Bh0, accB);
            accA = MFMA(A1h[1], Bh1, accA);
            accA = MFMA(A1h[1], Bl1, accA);
            accA = MFMA(A1l[1], Bh1, accA);
        }
        {
            const float gi = fsig  (accA[0] + accB[0]);
            const float gf = fsig  (accA[1] + accB[1]);
            const float gz = ftanhf(accA[2] + accB[2]);
            const float go = fsig  (accA[3] + accB[3]);
            c1 = gf * c1 + gi * gz;
            const float h = go * ftanhf(c1);
            HiLo s = split2(h);
            h1hi[wp][hw_off] = (unsigned short)s.hi;
            h1lo[wp][hw_off] = (unsigned short)s.lo;
        }
        __syncthreads();

        // ================= Layer 2 =================
        #pragma unroll
        for (int r = 0; r < 4; ++r) { accA[r] = bias2[r]; accB[r] = 0.f; }
        {
            short8 Bh0 = *(const short8*)(&h1hi[wp][off0]);
            short8 Bl0 = *(const short8*)(&h1lo[wp][off0]);
            short8 Bh1 = *(const short8*)(&h1hi[wp][off1]);
            short8 Bl1 = *(const short8*)(&h1lo[wp][off1]);
            accA = MFMA(A2h[0], Bh0, accA);
            accA = MFMA(A2h[0], Bl0, accA);
            accA = MFMA(A2l[0], Bh0, accA);
            accA = MFMA(A2h[1], Bh1, accA);
            accA = MFMA(A2h[1], Bl1, accA);
            accA = MFMA(A2l[1], Bh1, accA);
        }
        {
            short8 Dh0 = *(const short8*)(&h2hi[rp][off0]);
            short8 Dl0 = *(const short8*)(&h2lo[rp][off0]);
            short8 Dh1 = *(const short8*)(&h2hi[rp][off1]);
            short8 Dl1 = *(const short8*)(&h2lo[rp][off1]);
            accB = MFMA(A2h[2], Dh0, accB);
            accB = MFMA(A2h[2], Dl0, accB);
            accB = MFMA(A2l[2], Dh0, accB);
            accB = MFMA(A2h[3], Dh1, accB);
            accB = MFMA(A2h[3], Dl1, accB);
            accB = MFMA(A2l[3], Dh1, accB);
        }
        {
            const float gi = fsig  (accA[0] + accB[0]);
            const float gf = fsig  (accA[1] + accB[1]);
            const float gz = ftanhf(accA[2] + accB[2]);
            const float go = fsig  (accA[3] + accB[3]);
            c2 = gf * c2 + gi * gz;
            const float h = go * ftanhf(c2);
            HiLo s = split2(h);
            h2hi[wp][hw_off] = (unsigned short)s.hi;
            h2lo[wp][hw_off] = (unsigned short)s.lo;
            if (t == TT - 1) h2f[b * HF + jmine] = h;
        }
        __syncthreads();
    }

    // ================= FC epilogue =================
    if (tid < MT * OO) {
        const int bb = tid / OO, o = tid - bb * OO;
        float acc = bfc[o];
        const float* wr = Wfc + o * HH;
        const float* hr = h2f + bb * HF;
        #pragma unroll
        for (int j = 0; j < HH; ++j) acc += wr[j] * hr[j];
        out[((size_t)blockIdx.x * MT + bb) * OO + o] = acc;
    }
}

extern "C" void kernel_launch(void* const* d_in, const int* in_sizes, int n_in,
                              void* d_out, int out_size, void* d_ws, size_t ws_size,
                              hipStream_t stream) {
    const float* x    = (const float*)d_in[0];
    const float* Wih0 = (const float*)d_in[1];
    const float* Whh0 = (const float*)d_in[2];
    const float* bih0 = (const float*)d_in[3];
    const float* bhh0 = (const float*)d_in[4];
    const float* Wih1 = (const float*)d_in[5];
    const float* Whh1 = (const float*)d_in[6];
    const float* bih1 = (const float*)d_in[7];
    const float* bhh1 = (const float*)d_in[8];
    const float* Wfc  = (const float*)d_in[9];
    const float* bfc  = (const float*)d_in[10];
    float* out = (float*)d_out;

    dim3 grid(4096 / MT), block(NTHR);
    lstm_mfma3<<<grid, block, 0, stream>>>(x, Wih0, Whh0, bih0, bhh0,
                                           Wih1, Whh1, bih1, bhh1,
                                           Wfc, bfc, out);
}

// Round 8
// 417.654 us; speedup vs baseline: 1.2399x; 1.2399x over previous
//
#include <hip/hip_runtime.h>

// StockLSTM, merged-pipeline MFMA version.
// - A=weights (gate rows), B=state (16 batch cols); gates+cell update in-register.
// - ONE barrier per step: interval i computes L2(i) and L1(i+1) together
//   (L1(t+1) needs only h1(t); h1 fragments shared between both layers).
// - x pre-split to bf16 hi/lo in LDS per 64-step chunk; per-step x B-frag is
//   2 broadcast ds_read_b128 (A-side weight rows k>=5 are zero, so lanes q>0
//   may read duplicate data safely; pads zeroed once to avoid 0*Inf).
// - h state stored chunk-major: short offset ((k>>3)*16 + batch)*8 -> the
//   fragment read is exactly lane*16B (natural conflict-minimal b128 pattern).

#define TT   256
#define II   5
#define HH   64
#define OO   25
#define MT   16
#define NTHR 1024
#define XP   520        // x chunk row stride (ushorts) per batch row: 64*8 + 8 skew
#define HSZ  1024       // h parity block: 64 k * 16 batch shorts
#define HF   65         // h2f row stride (floats)

typedef __attribute__((ext_vector_type(8))) short  short8;
typedef __attribute__((ext_vector_type(4))) float  floatx4;

#define MFMA(a, b, c) __builtin_amdgcn_mfma_f32_16x16x32_bf16(a, b, c, 0, 0, 0)

__device__ __forceinline__ float frcp(float x) { return __builtin_amdgcn_rcpf(x); }
__device__ __forceinline__ float fsig(float x) {
    return frcp(1.f + __builtin_amdgcn_exp2f(x * -1.44269504f));
}
__device__ __forceinline__ float ftanhf(float x) {
    return 1.f - 2.f * frcp(1.f + __builtin_amdgcn_exp2f(x * 2.88539008f));
}
__device__ __forceinline__ unsigned short bf16_rne(float f) {
    unsigned int u = __builtin_bit_cast(unsigned int, f);
    u += 0x7FFFu + ((u >> 16) & 1u);
    return (unsigned short)(u >> 16);
}
__device__ __forceinline__ float bf16_f(unsigned short h) {
    unsigned int u = ((unsigned int)h) << 16;
    return __builtin_bit_cast(float, u);
}
struct HiLo { short hi, lo; };
__device__ __forceinline__ HiLo split2(float v) {
    HiLo r;
    unsigned short h = bf16_rne(v);
    r.hi = (short)h;
    r.lo = (short)bf16_rne(v - bf16_f(h));
    return r;
}
__device__ __forceinline__ float cell_update(const floatx4& aA, const floatx4& aB, float& c) {
    const float gi = fsig  (aA[0] + aB[0]);
    const float gf = fsig  (aA[1] + aB[1]);
    const float gz = ftanhf(aA[2] + aB[2]);
    const float go = fsig  (aA[3] + aB[3]);
    c = gf * c + gi * gz;
    return go * ftanhf(c);
}

__global__ __attribute__((amdgpu_flat_work_group_size(1024, 1024),
                          amdgpu_waves_per_eu(4, 4)))
void lstm_mfma4(const float* __restrict__ x,
                const float* __restrict__ Wih0, const float* __restrict__ Whh0,
                const float* __restrict__ bih0, const float* __restrict__ bhh0,
                const float* __restrict__ Wih1, const float* __restrict__ Whh1,
                const float* __restrict__ bih1, const float* __restrict__ bhh1,
                const float* __restrict__ Wfc,  const float* __restrict__ bfc,
                float* __restrict__ out)
{
    __shared__ __align__(16) unsigned short xhi[MT * XP];     // 16.6 KB
    __shared__ __align__(16) unsigned short xlo[MT * XP];     // 16.6 KB
    __shared__ __align__(16) unsigned short h1hi[2 * HSZ];    // 4 KB each
    __shared__ __align__(16) unsigned short h1lo[2 * HSZ];
    __shared__ __align__(16) unsigned short h2hi[2 * HSZ];
    __shared__ __align__(16) unsigned short h2lo[2 * HSZ];
    __shared__ __align__(16) float          h2f[MT * HF];     // 4.2 KB

    const int tid   = threadIdx.x;
    const int w     = tid >> 6;
    const int lane  = tid & 63;
    const int b     = lane & 15;      // batch col
    const int q     = lane >> 4;      // k-slice / C row-quad
    const int jmine = 4 * w + q;      // this lane's hidden unit
    // chunk-major h write offset for cell (batch=b, j=jmine):
    const int hw_off = ((jmine >> 3) * 16 + b) * 8 + (jmine & 7);
    const int ro     = lane * 8;      // fragment read offset (shorts): lane*16B

    // ---------------- A-fragment (weight) preload ----------------
    short8 A1h[2], A1l[2];   // Whh0 k-chunks
    short8 A2h[4], A2l[4];   // 0,1: Wih1 (h1 side); 2,3: Whh1 (h2 side)
    short8 Axwh, Axwl;       // Wih0: k<II valid, rest exact zero
    {
        const int rr = lane & 15;
        const int g  = (rr & 3) * 64 + 4 * w + (rr >> 2);
        #pragma unroll
        for (int c = 0; c < 2; ++c)
            #pragma unroll
            for (int jj = 0; jj < 8; ++jj) {
                HiLo s = split2(Whh0[g * HH + c * 32 + q * 8 + jj]);
                A1h[c][jj] = s.hi; A1l[c][jj] = s.lo;
            }
        #pragma unroll
        for (int c = 0; c < 4; ++c)
            #pragma unroll
            for (int jj = 0; jj < 8; ++jj) {
                const int k = c * 32 + q * 8 + jj;
                float wv = (k < HH) ? Wih1[g * HH + k] : Whh1[g * HH + (k - HH)];
                HiLo s = split2(wv);
                A2h[c][jj] = s.hi; A2l[c][jj] = s.lo;
            }
        #pragma unroll
        for (int jj = 0; jj < 8; ++jj) {
            const int k = q * 8 + jj;
            float wv = (k < II) ? Wih0[g * II + k] : 0.f;
            HiLo s = split2(wv);
            Axwh[jj] = s.hi; Axwl[jj] = s.lo;
        }
    }
    float bias1[4], bias2[4];
    #pragma unroll
    for (int r = 0; r < 4; ++r) {
        const int g = r * 64 + jmine;
        bias1[r] = bih0[g] + bhh0[g];
        bias2[r] = bih1[g] + bhh1[g];
    }

    // ---------------- zero LDS (h bufs + x pads; one-time) ----------------
    for (int i = tid; i < MT * XP / 2; i += NTHR) {
        ((unsigned int*)xhi)[i] = 0u;
        ((unsigned int*)xlo)[i] = 0u;
    }
    for (int i = tid; i < HSZ; i += NTHR) {   // HSZ uints = full [2*HSZ] shorts
        ((unsigned int*)h1hi)[i] = 0u;
        ((unsigned int*)h1lo)[i] = 0u;
        ((unsigned int*)h2hi)[i] = 0u;
        ((unsigned int*)h2lo)[i] = 0u;
    }
    float c1 = 0.f, c2 = 0.f;
    __syncthreads();

    const int blockBase = blockIdx.x * MT;

    // ---- x chunk refill (thread (b,dt) handles one timestep's 5 inputs) ----
    auto refill_x = [&](int t0) {
        const int rb = tid >> 6, dt = tid & 63;
        const float* src = x + ((size_t)(blockBase + rb) * TT + t0 + dt) * II;
        unsigned short* ph = xhi + rb * XP + dt * 8;
        unsigned short* pl = xlo + rb * XP + dt * 8;
        #pragma unroll
        for (int ii = 0; ii < II; ++ii) {
            HiLo s = split2(src[ii]);
            ph[ii] = (unsigned short)s.hi;
            pl[ii] = (unsigned short)s.lo;
        }
    };

    // ================= prologue: L1(0) (h1,c1 start at zero) =================
    refill_x(0);
    __syncthreads();
    {
        short8 Bxh = *(const short8*)(xhi + b * XP);
        short8 Bxl = *(const short8*)(xlo + b * XP);
        floatx4 aA = {bias1[0], bias1[1], bias1[2], bias1[3]};
        aA = MFMA(Axwh, Bxh, aA);
        aA = MFMA(Axwh, Bxl, aA);
        aA = MFMA(Axwl, Bxh, aA);
        floatx4 zero = {0.f, 0.f, 0.f, 0.f};
        const float h = cell_update(aA, zero, c1);
        HiLo s = split2(h);
        h1hi[0 * HSZ + hw_off] = (unsigned short)s.hi;   // L1(0) writes parity 0
        h1lo[0 * HSZ + hw_off] = (unsigned short)s.lo;
    }
    __syncthreads();

    // ================= merged main loop: L2(i) + L1(i+1) =================
    for (int i = 0; i < TT - 1; ++i) {
        if (((i + 1) & 63) == 0) {
            refill_x(i + 1);
            __syncthreads();
        }
        const int wp = i & 1, rp = wp ^ 1;
        const int dt = (i + 1) & 63;

        // ---- LDS reads (h1 shared by both layers) ----
        short8 H1h0 = *(const short8*)(h1hi + wp * HSZ + ro);
        short8 H1l0 = *(const short8*)(h1lo + wp * HSZ + ro);
        short8 H1h1 = *(const short8*)(h1hi + wp * HSZ + 512 + ro);
        short8 H1l1 = *(const short8*)(h1lo + wp * HSZ + 512 + ro);
        short8 H2h0 = *(const short8*)(h2hi + rp * HSZ + ro);
        short8 H2l0 = *(const short8*)(h2lo + rp * HSZ + ro);
        short8 H2h1 = *(const short8*)(h2hi + rp * HSZ + 512 + ro);
        short8 H2l1 = *(const short8*)(h2lo + rp * HSZ + 512 + ro);
        short8 Bxh  = *(const short8*)(xhi + b * XP + dt * 8);
        short8 Bxl  = *(const short8*)(xlo + b * XP + dt * 8);

        // ---- L2(i): gates from [h1(i); h2(i-1)] ----
        floatx4 a2A = {bias2[0], bias2[1], bias2[2], bias2[3]};
        floatx4 a2B = {0.f, 0.f, 0.f, 0.f};
        a2A = MFMA(A2h[0], H1h0, a2A);
        a2A = MFMA(A2h[0], H1l0, a2A);
        a2A = MFMA(A2l[0], H1h0, a2A);
        a2A = MFMA(A2h[1], H1h1, a2A);
        a2A = MFMA(A2h[1], H1l1, a2A);
        a2A = MFMA(A2l[1], H1h1, a2A);
        a2B = MFMA(A2h[2], H2h0, a2B);
        a2B = MFMA(A2h[2], H2l0, a2B);
        a2B = MFMA(A2l[2], H2h0, a2B);
        a2B = MFMA(A2h[3], H2h1, a2B);
        a2B = MFMA(A2h[3], H2l1, a2B);
        a2B = MFMA(A2l[3], H2h1, a2B);

        // ---- L1(i+1): gates from [x(i+1); h1(i)] ----
        floatx4 a1A = {bias1[0], bias1[1], bias1[2], bias1[3]};
        floatx4 a1B = {0.f, 0.f, 0.f, 0.f};
        a1A = MFMA(Axwh, Bxh, a1A);
        a1A = MFMA(Axwh, Bxl, a1A);
        a1A = MFMA(Axwl, Bxh, a1A);
        a1B = MFMA(A1h[0], H1h0, a1B);
        a1B = MFMA(A1h[0], H1l0, a1B);
        a1B = MFMA(A1l[0], H1h0, a1B);
        a1A = MFMA(A1h[1], H1h1, a1A);
        a1A = MFMA(A1h[1], H1l1, a1A);
        a1A = MFMA(A1l[1], H1h1, a1A);

        // ---- cell updates ----
        {
            const float h = cell_update(a2A, a2B, c2);   // h2(i) -> parity wp
            HiLo s = split2(h);
            h2hi[wp * HSZ + hw_off] = (unsigned short)s.hi;
            h2lo[wp * HSZ + hw_off] = (unsigned short)s.lo;
        }
        {
            const float h = cell_update(a1A, a1B, c1);   // h1(i+1) -> parity rp
            HiLo s = split2(h);
            h1hi[rp * HSZ + hw_off] = (unsigned short)s.hi;
            h1lo[rp * HSZ + hw_off] = (unsigned short)s.lo;
        }
        __syncthreads();
    }

    // ================= epilogue: L2(255) =================
    {
        const int wp = 1, rp = 0;   // 255&1 = 1
        short8 H1h0 = *(const short8*)(h1hi + wp * HSZ + ro);
        short8 H1l0 = *(const short8*)(h1lo + wp * HSZ + ro);
        short8 H1h1 = *(const short8*)(h1hi + wp * HSZ + 512 + ro);
        short8 H1l1 = *(const short8*)(h1lo + wp * HSZ + 512 + ro);
        short8 H2h0 = *(const short8*)(h2hi + rp * HSZ + ro);
        short8 H2l0 = *(const short8*)(h2lo + rp * HSZ + ro);
        short8 H2h1 = *(const short8*)(h2hi + rp * HSZ + 512 + ro);
        short8 H2l1 = *(const short8*)(h2lo + rp * HSZ + 512 + ro);
        floatx4 a2A = {bias2[0], bias2[1], bias2[2], bias2[3]};
        floatx4 a2B = {0.f, 0.f, 0.f, 0.f};
        a2A = MFMA(A2h[0], H1h0, a2A);
        a2A = MFMA(A2h[0], H1l0, a2A);
        a2A = MFMA(A2l[0], H1h0, a2A);
        a2A = MFMA(A2h[1], H1h1, a2A);
        a2A = MFMA(A2h[1], H1l1, a2A);
        a2A = MFMA(A2l[1], H1h1, a2A);
        a2B = MFMA(A2h[2], H2h0, a2B);
        a2B = MFMA(A2h[2], H2l0, a2B);
        a2B = MFMA(A2l[2], H2h0, a2B);
        a2B = MFMA(A2h[3], H2h1, a2B);
        a2B = MFMA(A2h[3], H2l1, a2B);
        a2B = MFMA(A2l[3], H2h1, a2B);
        const float h = cell_update(a2A, a2B, c2);
        h2f[b * HF + jmine] = h;
    }
    __syncthreads();

    // ================= FC epilogue =================
    if (tid < MT * OO) {
        const int bb = tid / OO, o = tid - bb * OO;
        float acc = bfc[o];
        const float* wr = Wfc + o * HH;
        const float* hr = h2f + bb * HF;
        #pragma unroll
        for (int j = 0; j < HH; ++j) acc += wr[j] * hr[j];
        out[((size_t)blockIdx.x * MT + bb) * OO + o] = acc;
    }
}

extern "C" void kernel_launch(void* const* d_in, const int* in_sizes, int n_in,
                              void* d_out, int out_size, void* d_ws, size_t ws_size,
                              hipStream_t stream) {
    const float* x    = (const float*)d_in[0];
    const float* Wih0 = (const float*)d_in[1];
    const float* Whh0 = (const float*)d_in[2];
    const float* bih0 = (const float*)d_in[3];
    const float* bhh0 = (const float*)d_in[4];
    const float* Wih1 = (const float*)d_in[5];
    const float* Whh1 = (const float*)d_in[6];
    const float* bih1 = (const float*)d_in[7];
    const float* bhh1 = (const float*)d_in[8];
    const float* Wfc  = (const float*)d_in[9];
    const float* bfc  = (const float*)d_in[10];
    float* out = (float*)d_out;

    dim3 grid(4096 / MT), block(NTHR);
    lstm_mfma4<<<grid, block, 0, stream>>>(x, Wih0, Whh0, bih0, bhh0,
                                           Wih1, Whh1, bih1, bhh1,
                                           Wfc, bfc, out);
}

// Round 9
// 359.254 us; speedup vs baseline: 1.4415x; 1.1626x over previous
//
#include <hip/hip_runtime.h>

// StockLSTM, merged-pipeline MFMA version, 2-term split.
// R8 analysis: wall/step = MFMA-phase + VALU-phase in series (barrier-locked
// waves), plus ~18 dword/thread spills. This round: drop weight-lo MFMA terms
// (weights bf16-rounded; state keeps hi+lo) -> 14 MFMAs/step (was 21) and
// -28 weight VGPRs -> no spills. Everything else = R8 (one barrier/step,
// chunk-major h layout, x pre-split in LDS).

#define TT   256
#define II   5
#define HH   64
#define OO   25
#define MT   16
#define NTHR 1024
#define XP   520        // x chunk row stride (ushorts): 64*8 + 8 skew
#define HSZ  1024       // h parity block: 64 k * 16 batch shorts
#define HF   65         // h2f row stride (floats)

typedef __attribute__((ext_vector_type(8))) short  short8;
typedef __attribute__((ext_vector_type(4))) float  floatx4;

#define MFMA(a, b, c) __builtin_amdgcn_mfma_f32_16x16x32_bf16(a, b, c, 0, 0, 0)

__device__ __forceinline__ float frcp(float x) { return __builtin_amdgcn_rcpf(x); }
__device__ __forceinline__ float fsig(float x) {
    return frcp(1.f + __builtin_amdgcn_exp2f(x * -1.44269504f));
}
__device__ __forceinline__ float ftanhf(float x) {
    return 1.f - 2.f * frcp(1.f + __builtin_amdgcn_exp2f(x * 2.88539008f));
}
__device__ __forceinline__ unsigned short bf16_rne(float f) {
    unsigned int u = __builtin_bit_cast(unsigned int, f);
    u += 0x7FFFu + ((u >> 16) & 1u);
    return (unsigned short)(u >> 16);
}
__device__ __forceinline__ float bf16_f(unsigned short h) {
    unsigned int u = ((unsigned int)h) << 16;
    return __builtin_bit_cast(float, u);
}
struct HiLo { short hi, lo; };
__device__ __forceinline__ HiLo split2(float v) {
    HiLo r;
    unsigned short h = bf16_rne(v);
    r.hi = (short)h;
    r.lo = (short)bf16_rne(v - bf16_f(h));
    return r;
}
__device__ __forceinline__ float cell_update(const floatx4& aA, const floatx4& aB, float& c) {
    const float gi = fsig  (aA[0] + aB[0]);
    const float gf = fsig  (aA[1] + aB[1]);
    const float gz = ftanhf(aA[2] + aB[2]);
    const float go = fsig  (aA[3] + aB[3]);
    c = gf * c + gi * gz;
    return go * ftanhf(c);
}

__global__ __attribute__((amdgpu_flat_work_group_size(1024, 1024),
                          amdgpu_waves_per_eu(4, 4)))
void lstm_mfma5(const float* __restrict__ x,
                const float* __restrict__ Wih0, const float* __restrict__ Whh0,
                const float* __restrict__ bih0, const float* __restrict__ bhh0,
                const float* __restrict__ Wih1, const float* __restrict__ Whh1,
                const float* __restrict__ bih1, const float* __restrict__ bhh1,
                const float* __restrict__ Wfc,  const float* __restrict__ bfc,
                float* __restrict__ out)
{
    __shared__ __align__(16) unsigned short xhi[MT * XP];
    __shared__ __align__(16) unsigned short xlo[MT * XP];
    __shared__ __align__(16) unsigned short h1hi[2 * HSZ];
    __shared__ __align__(16) unsigned short h1lo[2 * HSZ];
    __shared__ __align__(16) unsigned short h2hi[2 * HSZ];
    __shared__ __align__(16) unsigned short h2lo[2 * HSZ];
    __shared__ __align__(16) float          h2f[MT * HF];

    const int tid   = threadIdx.x;
    const int w     = tid >> 6;
    const int lane  = tid & 63;
    const int b     = lane & 15;      // batch col
    const int q     = lane >> 4;      // k-slice / C row-quad
    const int jmine = 4 * w + q;
    const int hw_off = ((jmine >> 3) * 16 + b) * 8 + (jmine & 7);
    const int ro     = lane * 8;      // fragment read offset: lane*16B

    // ---------------- A-fragment (weight) preload — hi only ----------------
    short8 A1h[2];   // Whh0 k-chunks
    short8 A2h[4];   // 0,1: Wih1 (h1 side); 2,3: Whh1 (h2 side)
    short8 Axwh;     // Wih0: k<II valid, rest exact zero
    {
        const int rr = lane & 15;
        const int g  = (rr & 3) * 64 + 4 * w + (rr >> 2);
        #pragma unroll
        for (int c = 0; c < 2; ++c)
            #pragma unroll
            for (int jj = 0; jj < 8; ++jj)
                A1h[c][jj] = (short)bf16_rne(Whh0[g * HH + c * 32 + q * 8 + jj]);
        #pragma unroll
        for (int c = 0; c < 4; ++c)
            #pragma unroll
            for (int jj = 0; jj < 8; ++jj) {
                const int k = c * 32 + q * 8 + jj;
                float wv = (k < HH) ? Wih1[g * HH + k] : Whh1[g * HH + (k - HH)];
                A2h[c][jj] = (short)bf16_rne(wv);
            }
        #pragma unroll
        for (int jj = 0; jj < 8; ++jj) {
            const int k = q * 8 + jj;
            Axwh[jj] = (k < II) ? (short)bf16_rne(Wih0[g * II + k]) : (short)0;
        }
    }
    float bias1[4], bias2[4];
    #pragma unroll
    for (int r = 0; r < 4; ++r) {
        const int g = r * 64 + jmine;
        bias1[r] = bih0[g] + bhh0[g];
        bias2[r] = bih1[g] + bhh1[g];
    }

    // ---------------- zero LDS ----------------
    for (int i = tid; i < MT * XP / 2; i += NTHR) {
        ((unsigned int*)xhi)[i] = 0u;
        ((unsigned int*)xlo)[i] = 0u;
    }
    for (int i = tid; i < HSZ; i += NTHR) {
        ((unsigned int*)h1hi)[i] = 0u;
        ((unsigned int*)h1lo)[i] = 0u;
        ((unsigned int*)h2hi)[i] = 0u;
        ((unsigned int*)h2lo)[i] = 0u;
    }
    float c1 = 0.f, c2 = 0.f;
    __syncthreads();

    const int blockBase = blockIdx.x * MT;

    auto refill_x = [&](int t0) {
        const int rb = tid >> 6, dt = tid & 63;
        const float* src = x + ((size_t)(blockBase + rb) * TT + t0 + dt) * II;
        unsigned short* ph = xhi + rb * XP + dt * 8;
        unsigned short* pl = xlo + rb * XP + dt * 8;
        #pragma unroll
        for (int ii = 0; ii < II; ++ii) {
            HiLo s = split2(src[ii]);
            ph[ii] = (unsigned short)s.hi;
            pl[ii] = (unsigned short)s.lo;
        }
    };

    // ================= prologue: L1(0) =================
    refill_x(0);
    __syncthreads();
    {
        short8 Bxh = *(const short8*)(xhi + b * XP);
        short8 Bxl = *(const short8*)(xlo + b * XP);
        floatx4 aA = {bias1[0], bias1[1], bias1[2], bias1[3]};
        aA = MFMA(Axwh, Bxh, aA);
        aA = MFMA(Axwh, Bxl, aA);
        floatx4 zero = {0.f, 0.f, 0.f, 0.f};
        const float h = cell_update(aA, zero, c1);
        HiLo s = split2(h);
        h1hi[0 * HSZ + hw_off] = (unsigned short)s.hi;
        h1lo[0 * HSZ + hw_off] = (unsigned short)s.lo;
    }
    __syncthreads();

    // ================= merged main loop: L2(i) + L1(i+1) =================
    for (int i = 0; i < TT - 1; ++i) {
        if (((i + 1) & 63) == 0) {
            refill_x(i + 1);
            __syncthreads();
        }
        const int wp = i & 1, rp = wp ^ 1;
        const int dt = (i + 1) & 63;

        short8 H1h0 = *(const short8*)(h1hi + wp * HSZ + ro);
        short8 H1l0 = *(const short8*)(h1lo + wp * HSZ + ro);
        short8 H1h1 = *(const short8*)(h1hi + wp * HSZ + 512 + ro);
        short8 H1l1 = *(const short8*)(h1lo + wp * HSZ + 512 + ro);
        short8 H2h0 = *(const short8*)(h2hi + rp * HSZ + ro);
        short8 H2l0 = *(const short8*)(h2lo + rp * HSZ + ro);
        short8 H2h1 = *(const short8*)(h2hi + rp * HSZ + 512 + ro);
        short8 H2l1 = *(const short8*)(h2lo + rp * HSZ + 512 + ro);
        short8 Bxh  = *(const short8*)(xhi + b * XP + dt * 8);
        short8 Bxl  = *(const short8*)(xlo + b * XP + dt * 8);

        // ---- L2(i): gates from [h1(i); h2(i-1)] ----
        floatx4 a2A = {bias2[0], bias2[1], bias2[2], bias2[3]};
        floatx4 a2B = {0.f, 0.f, 0.f, 0.f};
        a2A = MFMA(A2h[0], H1h0, a2A);
        a2A = MFMA(A2h[0], H1l0, a2A);
        a2A = MFMA(A2h[1], H1h1, a2A);
        a2A = MFMA(A2h[1], H1l1, a2A);
        a2B = MFMA(A2h[2], H2h0, a2B);
        a2B = MFMA(A2h[2], H2l0, a2B);
        a2B = MFMA(A2h[3], H2h1, a2B);
        a2B = MFMA(A2h[3], H2l1, a2B);

        // ---- L1(i+1): gates from [x(i+1); h1(i)] ----
        floatx4 a1A = {bias1[0], bias1[1], bias1[2], bias1[3]};
        floatx4 a1B = {0.f, 0.f, 0.f, 0.f};
        a1A = MFMA(Axwh, Bxh, a1A);
        a1A = MFMA(Axwh, Bxl, a1A);
        a1B = MFMA(A1h[0], H1h0, a1B);
        a1B = MFMA(A1h[0], H1l0, a1B);
        a1A = MFMA(A1h[1], H1h1, a1A);
        a1A = MFMA(A1h[1], H1l1, a1A);

        // ---- cell updates ----
        {
            const float h = cell_update(a2A, a2B, c2);
            HiLo s = split2(h);
            h2hi[wp * HSZ + hw_off] = (unsigned short)s.hi;
            h2lo[wp * HSZ + hw_off] = (unsigned short)s.lo;
        }
        {
            const float h = cell_update(a1A, a1B, c1);
            HiLo s = split2(h);
            h1hi[rp * HSZ + hw_off] = (unsigned short)s.hi;
            h1lo[rp * HSZ + hw_off] = (unsigned short)s.lo;
        }
        __syncthreads();
    }

    // ================= epilogue: L2(255) =================
    {
        const int wp = 1, rp = 0;
        short8 H1h0 = *(const short8*)(h1hi + wp * HSZ + ro);
        short8 H1l0 = *(const short8*)(h1lo + wp * HSZ + ro);
        short8 H1h1 = *(const short8*)(h1hi + wp * HSZ + 512 + ro);
        short8 H1l1 = *(const short8*)(h1lo + wp * HSZ + 512 + ro);
        short8 H2h0 = *(const short8*)(h2hi + rp * HSZ + ro);
        short8 H2l0 = *(const short8*)(h2lo + rp * HSZ + ro);
        short8 H2h1 = *(const short8*)(h2hi + rp * HSZ + 512 + ro);
        short8 H2l1 = *(const short8*)(h2lo + rp * HSZ + 512 + ro);
        floatx4 a2A = {bias2[0], bias2[1], bias2[2], bias2[3]};
        floatx4 a2B = {0.f, 0.f, 0.f, 0.f};
        a2A = MFMA(A2h[0], H1h0, a2A);
        a2A = MFMA(A2h[0], H1l0, a2A);
        a2A = MFMA(A2h[1], H1h1, a2A);
        a2A = MFMA(A2h[1], H1l1, a2A);
        a2B = MFMA(A2h[2], H2h0, a2B);
        a2B = MFMA(A2h[2], H2l0, a2B);
        a2B = MFMA(A2h[3], H2h1, a2B);
        a2B = MFMA(A2h[3], H2l1, a2B);
        const float h = cell_update(a2A, a2B, c2);
        h2f[b * HF + jmine] = h;
    }
    __syncthreads();

    // ================= FC epilogue =================
    if (tid < MT * OO) {
        const int bb = tid / OO, o = tid - bb * OO;
        float acc = bfc[o];
        const float* wr = Wfc + o * HH;
        const float* hr = h2f + bb * HF;
        #pragma unroll
        for (int j = 0; j < HH; ++j) acc += wr[j] * hr[j];
        out[((size_t)blockIdx.x * MT + bb) * OO + o] = acc;
    }
}

extern "C" void kernel_launch(void* const* d_in, const int* in_sizes, int n_in,
                              void* d_out, int out_size, void* d_ws, size_t ws_size,
                              hipStream_t stream) {
    const float* x    = (const float*)d_in[0];
    const float* Wih0 = (const float*)d_in[1];
    const float* Whh0 = (const float*)d_in[2];
    const float* bih0 = (const float*)d_in[3];
    const float* bhh0 = (const float*)d_in[4];
    const float* Wih1 = (const float*)d_in[5];
    const float* Whh1 = (const float*)d_in[6];
    const float* bih1 = (const float*)d_in[7];
    const float* bhh1 = (const float*)d_in[8];
    const float* Wfc  = (const float*)d_in[9];
    const float* bfc  = (const float*)d_in[10];
    float* out = (float*)d_out;

    dim3 grid(4096 / MT), block(NTHR);
    lstm_mfma5<<<grid, block, 0, stream>>>(x, Wih0, Whh0, bih0, bhh0,
                                           Wih1, Whh1, bih1, bhh1,
                                           Wfc, bfc, out);
}